// Round 5
// baseline (83.745 us; speedup 1.0000x reference)
//
#include <hip/hip_runtime.h>
#include <stdint.h>

typedef unsigned long long u64;

#define KCAND 9
#define BATCH 16
#define NPRED 30000
#define NGT   64
#define TPB   512                  // 8 waves
#define GTA   4                    // GTs per block
#define UNRF  4                    // float4 (=2-point) loads per thread per iter
#define PPT   (TPB * UNRF * 2)     // 4096 points per block-iteration
#define NT    8                    // 8 * 4096 = 32768 slots
#define PSTR  32768                // padded points per image (pow2)
#define CAP   128                  // candidate slots per GT (expected ~12)
#define SMARG 1e-5f                // s-space superset margin (err bound ~2e-6)
#define INITKEY 0x7F800000FFFFFFFFULL
#define FINF  __uint_as_float(0x7F800000u)
#define FNAN  __uint_as_float(0x7FC00000u)
#define SENT  (~0ULL)

__device__ __forceinline__ float wave_min_f(float v) {
#pragma unroll
    for (int s = 1; s < 64; s <<= 1) v = fminf(v, __shfl_xor(v, s, 64));
    return v;
}
__device__ __forceinline__ u64 wave_min_u64(u64 v) {
#pragma unroll
    for (int s = 1; s < 64; s <<= 1) {
        u64 o = __shfl_xor(v, s, 64);
        v = o < v ? o : v;
    }
    return v;
}

// pre-pass: compact (xy, r=0.5*(x^2+y^2)) with pad sentinels (xy=+inf, r=NaN).
// NaN r makes pad s-scores NaN -> dropped by fminf and by s<=T (both NaN-safe).
__global__ __launch_bounds__(256) void compact_xyr(
    const float* __restrict__ pred, float2* __restrict__ xy,
    float* __restrict__ rr)
{
    int e = blockIdx.x * 256 + threadIdx.x;   // over BATCH*PSTR (exact multiple)
    int b = e >> 15;                          // PSTR = 32768
    int i = e & (PSTR - 1);
    float2 v; float r;
    if (i < NPRED) {
        float4 p = ((const float4*)pred)[(size_t)b * NPRED + i];
        v = make_float2(p.x, p.y);
        r = __fadd_rn(__fmul_rn(0.5f * p.x, p.x), __fmul_rn(0.5f * p.y, p.y));
    } else {
        v = make_float2(FINF, FINF);
        r = FNAN;
    }
    xy[e] = v;
    rr[e] = r;
}

// exact reference-rounded dist^2 (keys/ordering ONLY come from this)
#define DIST(GX, GY, PX, PY, D)                                              \
    { float _dx = __fsub_rn(GX, PX), _dy = __fsub_rn(GY, PY);                \
      D = __fadd_rn(__fmul_rn(_dx, _dx), __fmul_rn(_dy, _dy)); }

template <bool PADDED>
__global__ __launch_bounds__(TPB, 2) void atss4(
    const float2* __restrict__ xy,    // [B][PSTR] compact xy (PADDED)
    const float*  __restrict__ rr,    // [B][PSTR] compact r  (PADDED)
    const float*  __restrict__ pred,  // [B, N, 4] cxcywh
    const float*  __restrict__ gt,    // [B, G, 4] cxcywh
    float* __restrict__ out)          // [4][B*G*K] float32
{
#pragma clang fp contract(off)
    const int tid  = threadIdx.x;
    const int lane = tid & 63;
    const int wv   = tid >> 6;

    // grid = 256: bits[2:0]=xcd(img low3), [6:3]=gt-group, [7]=img-high.
    const int bi = blockIdx.x;
    const int b  = (bi & 7) + 8 * (bi >> 7);
    const int g0 = ((bi >> 3) & 15) * GTA;

    const float4* gt4 = (const float4*)gt;
    const int w0 = b * NGT + g0;
    const float4 gq0 = gt4[w0],     gq1 = gt4[w0 + 1];
    const float4 gq2 = gt4[w0 + 2], gq3 = gt4[w0 + 3];
    const float aX = gq0.x, aY = gq0.y;
    const float bX = gq1.x, bY = gq1.y;
    const float cX = gq2.x, cY = gq2.y;
    const float dX = gq3.x, dY = gq3.y;
    const float nAx = -aX, nAy = -aY, nBx = -bX, nBy = -bY;
    const float nCx = -cX, nCy = -cY, nDx = -dX, nDy = -dY;

    const float4* p4 = (const float4*)pred + (size_t)b * NPRED;
    const float2* x2 = PADDED ? (xy + (size_t)b * PSTR) : (const float2*)0;
    const float4* x4 = (const float4*)x2;
    const float2* r2 = PADDED ? (const float2*)(rr + (size_t)b * PSTR)
                              : (const float2*)0;

    __shared__ float tmins[GTA][TPB];   // 8 KB per-thread s-mins
    __shared__ float tg[GTA];           // per-GT s-threshold (incl. margin)
    __shared__ int   cnt[GTA];
    __shared__ u64   cand[GTA][CAP];    // 4 KB

    if (tid < GTA) cnt[tid] = 0;

    // ===== pass 1: per-thread running min of s = r - gx*px - gy*py ==========
    // (monotone surrogate of d^2/2 per GT; 2 FMA + 1 min per point per GT)
    float lm0 = FINF, lm1 = FINF, lm2 = FINF, lm3 = FINF;
#define S1(PX, PY, R)                                                        \
    { lm0 = fminf(lm0, fmaf(nAx, PX, fmaf(nAy, PY, R)));                     \
      lm1 = fminf(lm1, fmaf(nBx, PX, fmaf(nBy, PY, R)));                     \
      lm2 = fminf(lm2, fmaf(nCx, PX, fmaf(nCy, PY, R)));                     \
      lm3 = fminf(lm3, fmaf(nDx, PX, fmaf(nDy, PY, R))); }

    if (PADDED) {
        for (int t = 0; t < NT; ++t) {
            const int f0 = t * (PPT / 2) + tid;
#pragma unroll
            for (int k = 0; k < UNRF; ++k) {
                float4 q  = x4[f0 + k * TPB];
                float2 rv = r2[f0 + k * TPB];
                S1(q.x, q.y, rv.x) S1(q.z, q.w, rv.y)
            }
        }
    } else {
        for (int t = 0; t < NT; ++t) {
#pragma unroll
            for (int j = 0; j < 2 * UNRF; ++j) {
                const int i = t * PPT + j * TPB + tid;
                const bool vv = i < NPRED;
                float4 q = p4[vv ? i : 0];
                float px = q.x, py = q.y;
                float r = vv ? __fadd_rn(__fmul_rn(0.5f * px, px),
                                         __fmul_rn(0.5f * py, py)) : FNAN;
                S1(px, py, r)
            }
        }
    }
#undef S1

    tmins[0][tid] = lm0; tmins[1][tid] = lm1;
    tmins[2][tid] = lm2; tmins[3][tid] = lm3;
    __syncthreads();

    // ===== threshold: 9th-smallest thread-min (s-space) + margin ============
    // <=8 points have s < s9 => <=8 threads have min < s9 => T >= s9.
    // Equal-removal only loosens T upward. +SMARG makes {s<=T} a proven
    // superset of the d^2-top-9 (cross-space rounding err < 2e-6 on [0,1]^2).
    if (wv < GTA) {
        float a[TPB / 64];
#pragma unroll
        for (int j = 0; j < TPB / 64; ++j) a[j] = tmins[wv][j * 64 + lane];
        float T = FINF;
#pragma unroll
        for (int r = 0; r < KCAND; ++r) {
            float ml = a[0];
#pragma unroll
            for (int j = 1; j < TPB / 64; ++j) ml = fminf(ml, a[j]);
            float m = wave_min_f(ml);
#pragma unroll
            for (int j = 0; j < TPB / 64; ++j) a[j] = (a[j] == m) ? FINF : a[j];
            T = m;
        }
        if (lane == 0) tg[wv] = T + SMARG;
    }
    __syncthreads();
    const float T0 = tg[0], T1 = tg[1], T2 = tg[2], T3 = tg[3];

    // ===== pass 2: s-filter rescan; candidates keyed by EXACT d^2 ===========
#define COLLECT(H, GX, GY, C, PX, PY, IDXE)                                  \
    { u64 bm = __ballot(H);                                                  \
      if (bm) {                                                              \
          int ldr = __ffsll(bm) - 1;                                         \
          int base = 0;                                                      \
          if (lane == ldr) base = atomicAdd(&cnt[C], (int)__popcll(bm));     \
          base = __shfl(base, ldr, 64);                                      \
          if (H) {                                                           \
              float dd; DIST(GX, GY, PX, PY, dd);                            \
              int slot = base + (int)__popcll(bm & ((1ULL << lane) - 1ULL)); \
              if (slot < CAP)                                                \
                  cand[C][slot] =                                            \
                      ((u64)__float_as_uint(dd) << 32) | (unsigned)(IDXE);   \
          } } }
#define S2(PX, PY, R, IDXE)                                                  \
    { float s0 = fmaf(nAx, PX, fmaf(nAy, PY, R));                            \
      float s1 = fmaf(nBx, PX, fmaf(nBy, PY, R));                            \
      float s2 = fmaf(nCx, PX, fmaf(nCy, PY, R));                            \
      float s3 = fmaf(nDx, PX, fmaf(nDy, PY, R));                            \
      bool h0 = s0 <= T0, h1 = s1 <= T1, h2 = s2 <= T2, h3 = s3 <= T3;       \
      if (__ballot(h0 | h1 | h2 | h3)) {                                     \
          COLLECT(h0, aX, aY, 0, PX, PY, IDXE)                               \
          COLLECT(h1, bX, bY, 1, PX, PY, IDXE)                               \
          COLLECT(h2, cX, cY, 2, PX, PY, IDXE)                               \
          COLLECT(h3, dX, dY, 3, PX, PY, IDXE)                               \
      } }

    if (PADDED) {
        for (int t = 0; t < NT; ++t) {
            const int f0 = t * (PPT / 2) + tid;
#pragma unroll
            for (int k = 0; k < UNRF; ++k) {
                float4 q  = x4[f0 + k * TPB];
                float2 rv = r2[f0 + k * TPB];
                S2(q.x, q.y, rv.x, 2 * (f0 + k * TPB))
                S2(q.z, q.w, rv.y, 2 * (f0 + k * TPB) + 1)
            }
        }
    } else {
        for (int t = 0; t < NT; ++t) {
#pragma unroll
            for (int j = 0; j < 2 * UNRF; ++j) {
                const int i = t * PPT + j * TPB + tid;
                const bool vv = i < NPRED;
                float4 q = p4[vv ? i : 0];
                float px = q.x, py = q.y;
                float r = vv ? __fadd_rn(__fmul_rn(0.5f * px, px),
                                         __fmul_rn(0.5f * py, py)) : FNAN;
                S2(px, py, r, i)
            }
        }
    }
#undef S2
#undef COLLECT
    __syncthreads();

    // ===== exact top-9 selection + epilogue: wave c -> GT c =================
    if (wv >= GTA) return;
    const int c = wv;
    const float gX = (c == 0) ? aX : (c == 1) ? bX : (c == 2) ? cX : dX;
    const float gY = (c == 0) ? aY : (c == 1) ? bY : (c == 2) ? cY : dY;
    const int n = cnt[c];                       // >=9 guaranteed (T >= s9)

    u64 fin = SENT;
    if (n <= CAP) {
        u64 k0 = (lane < n)      ? cand[c][lane]      : SENT;
        u64 k1 = (lane + 64 < n) ? cand[c][lane + 64] : SENT;
#pragma unroll
        for (int r = 0; r < KCAND; ++r) {
            u64 ml = k0 < k1 ? k0 : k1;
            u64 m = wave_min_u64(ml);
            if (lane == r) fin = m;
            if (k0 == m) k0 = SENT;             // keys unique (idx embedded)
            if (k1 == m) k1 = SENT;
        }
    } else {
        // overflow fallback (statistically never): exact sorted-insert over
        // all slots, gated by a d-space bound derived from the s-threshold:
        // s <= T  =>  d^2 <= 2*(T + C) + err,  C = 0.5*(gx^2+gy^2).
        const float Chat = __fadd_rn(__fmul_rn(0.5f * gX, gX),
                                     __fmul_rn(0.5f * gY, gY));
        const float Tcap = 2.0f * (tg[c] + Chat) + 1e-4f;
        u64 val = INITKEY;
        float Tf = Tcap;
        for (int i0 = 0; i0 < PSTR; i0 += 64) {
            const int i = i0 + lane;
            float px, py;
            if (PADDED) {
                float2 p = x2[i];  px = p.x;  py = p.y;   // pads +inf -> d inf
            } else {
                const bool vv = i < NPRED;
                float4 q = p4[vv ? i : 0];
                px = vv ? q.x : FINF;  py = vv ? q.y : FINF;
            }
            float d;  DIST(gX, gY, px, py, d);
            u64 pend = __ballot(d <= Tf);
            while (pend) {
                const int src = __ffsll(pend) - 1;
                pend &= pend - 1;
                const unsigned kd = __shfl(__float_as_uint(d), src, 64);
                const unsigned ki = (unsigned)(i0 + src);
                const u64 key = ((u64)kd << 32) | ki;
                u64 Tkey = __shfl(val, 8, 64);
                if (key < Tkey) {               // wave-uniform
                    const u64 ltm = __ballot(val < key) & 0x1FFULL;
                    const int pos = __popcll(ltm);
                    const u64 sh = __shfl_up(val, 1, 64);
                    if (lane < KCAND) {
                        if (lane == pos)      val = key;
                        else if (lane > pos)  val = sh;
                    }
                    Tkey = __shfl(val, 8, 64);
                    Tf = fminf(Tcap, __uint_as_float((unsigned)(Tkey >> 32)));
                    pend &= __ballot(d <= Tf);
                }
            }
        }
        fin = val;                              // lane r holds r-th smallest
    }

    const int g = g0 + c;
    const int w = b * NGT + g;
    const float4 gq = gt4[w];
    const float gcx = gq.x, gcy = gq.y;

    const bool active = (lane < KCAND);
    const unsigned idx = active ? (unsigned)(fin & 0xffffffffu) : 0u;

    float4 pbx = p4[idx];

    float gx1 = gcx - 0.5f * gq.z, gy1 = gcy - 0.5f * gq.w;
    float gx2 = gcx + 0.5f * gq.z, gy2 = gcy + 0.5f * gq.w;
    float kx1 = pbx.x - 0.5f * pbx.z, ky1 = pbx.y - 0.5f * pbx.w;
    float kx2 = pbx.x + 0.5f * pbx.z, ky2 = pbx.y + 0.5f * pbx.w;

    float ltx = fmaxf(gx1, kx1), lty = fmaxf(gy1, ky1);
    float rbx = fminf(gx2, kx2), rby = fminf(gy2, ky2);
    float wvd = fmaxf(rbx - ltx, 0.0f);
    float hvd = fmaxf(rby - lty, 0.0f);
    float inter  = wvd * hvd;
    float area_a = (gx2 - gx1) * (gy2 - gy1);
    float area_b = (kx2 - kx1) * (ky2 - ky1);
    float iou = inter / ((area_a + area_b) - inter);

    float v = active ? iou : 0.0f;
    float s = v;
#pragma unroll
    for (int m = 1; m < 64; m <<= 1) s += __shfl_xor(s, m, 64);
    float mean = s / 9.0f;

    float dev = active ? (iou - mean) : 0.0f;
    float ss = dev * dev;
#pragma unroll
    for (int m = 1; m < 64; m <<= 1) ss += __shfl_xor(ss, m, 64);
    float stdv = sqrtf(ss / 8.0f);    // ddof = 1
    float thr = mean + stdv;

    bool inside = (gx1 <= pbx.x) && (pbx.x <= gx2) &&
                  (gy1 <= pbx.y) && (pbx.y <= gy2);
    bool maskk = (iou >= thr) && inside;

    if (active) {
        const size_t chunk = (size_t)BATCH * NGT * KCAND;   // 9216
        const size_t o = (size_t)w * KCAND + lane;
        out[0 * chunk + o] = maskk ? (float)idx : -1.0f;    // pred_idx
        out[1 * chunk + o] = maskk ? (float)g   : -1.0f;    // gt_idx
        out[2 * chunk + o] = maskk ? 1.0f : 0.0f;           // mask
        out[3 * chunk + o] = iou;                           // ious
    }
}

extern "C" void kernel_launch(void* const* d_in, const int* in_sizes, int n_in,
                              void* d_out, int out_size, void* d_ws, size_t ws_size,
                              hipStream_t stream) {
    const float* pred = (const float*)d_in[0];   // [16, 30000, 4] f32
    const float* gtb  = (const float*)d_in[1];   // [16, 64, 4] f32
    float* out = (float*)d_out;

    const size_t nxy  = (size_t)BATCH * PSTR * sizeof(float2);   // 4.19 MB
    const size_t need = nxy + (size_t)BATCH * PSTR * sizeof(float); // 6.29 MB
    if (ws_size >= need) {
        float2* xy = (float2*)d_ws;
        float*  rr = (float*)((char*)d_ws + nxy);
        compact_xyr<<<BATCH * PSTR / 256, 256, 0, stream>>>(pred, xy, rr);
        atss4<true><<<BATCH * (NGT / GTA), TPB, 0, stream>>>(
            xy, rr, pred, gtb, out);
    } else {
        atss4<false><<<BATCH * (NGT / GTA), TPB, 0, stream>>>(
            nullptr, nullptr, pred, gtb, out);
    }
}